// Round 4
// baseline (454.585 us; speedup 1.0000x reference)
//
#include <hip/hip_runtime.h>
#include <hip/hip_cooperative_groups.h>

namespace cg = cooperative_groups;

#define LN_EPS 1e-5f

// ---------------------------------------------------------------------------
// Index algebra (verified passing rounds 2-3):
//   F[which][b][g][cc][cs*64+d] = P_{which}[b, s_i, h_i*64+d] + bias
//     s_i = (cc<2 ? 240+8*cc : 8*(cc-2)) + cs,  h_i = g*2 + (cc>>1)
//   Dt[b][gq][gk][cc][cs] = dot64(Fq, Fk) / 8
//   SFK[b][c][d] = 32 * sum_gv FK[b][gv][c>>3][(c&7)*64+d]  (pre-scaled)
//   attn weights: per (q,k) softmax over 32 c of (vq&vk ? Dt : 0);
//     masked (q,k) -> uniform 1/32.  A[c] = sum_k attn;  ctx = A @ SFK.
//   attn_out == 1.0 everywhere.
// Scratch (floats): F 32768 | Dt 1024 | SFK 4096 | ctx 262144 | ymid 262144
//   total 562176 floats = 2.2 MB  (fits d_ws plan-A, or attn_out region plan-B)
// ---------------------------------------------------------------------------

__device__ __forceinline__ bool sniff_mask_bytes(const unsigned int* m) {
    unsigned int acc = 0;
#pragma unroll
    for (int i = 0; i < 16; ++i) acc |= m[i];
    return acc > 1u;   // int32 mask words are 0/1; byte mask packs 4 bytes/word
}

__global__ __launch_bounds__(256, 4) void fused_all(
    const float* __restrict__ Qin, const float* __restrict__ Kin,
    const void* __restrict__ maskp,
    const float* __restrict__ WQ, const float* __restrict__ bQ,
    const float* __restrict__ WK, const float* __restrict__ bK,
    const float* __restrict__ Wo, const float* __restrict__ bo,
    const float* __restrict__ gamma, const float* __restrict__ beta,
    float* __restrict__ out, float* __restrict__ attnp,
    float* __restrict__ scr, int fill)
{
    cg::grid_group grid = cg::this_grid();
    __shared__ float smem[4096];               // 16 KB, reused per phase
    const int t  = threadIdx.x;
    const int nb = gridDim.x;

    float* Fg   = scr;                         // 32768
    float* Dt   = scr + 32768;                 // 1024
    float* SFK  = scr + 33792;                 // 4096 (pre-scaled x32)
    float* ctx  = scr + 37888;                 // 262144
    float* ymid = scr + 300032;                // 262144

    // ---- Phase A: projections -> F (8-lane split-K per output, shfl reduce)
    for (int vb = blockIdx.x; vb < 1024; vb += nb) {
        int slot = vb * 256 + t;
        int f = slot >> 3, part = t & 7;
        int d = f & 63, cs = (f >> 6) & 7, cc = (f >> 9) & 3,
            g = (f >> 11) & 3, b = (f >> 13) & 1, which = f >> 14;
        const float* In = which ? Kin : Qin;
        const float* W  = which ? WK  : WQ;
        int sbase = (cc < 2) ? (240 + 8 * cc) : (8 * (cc - 2));
        int n = (g * 2 + (cc >> 1)) * 64 + d;
        const float* xr = In + (b * 256 + sbase + cs) * 512 + part * 64;
        const float* wc = W + (part * 64) * 512 + n;
        float acc = 0.f;
#pragma unroll
        for (int m = 0; m < 64; ++m) acc += xr[m] * wc[m * 512];
        acc += __shfl_xor(acc, 1);
        acc += __shfl_xor(acc, 2);
        acc += __shfl_xor(acc, 4);
        if (part == 0) Fg[f] = acc + (which ? bK[n] : bQ[n]);
    }
    __threadfence();
    grid.sync();

    // ---- Phase B: Dt (8-lane dot + shfl) and SFK (pre-scaled x32)
    for (int vb = blockIdx.x; vb < 48; vb += nb) {
        int slot = vb * 256 + t;
        if (slot < 8192) {
            int part = slot & 7, e = slot >> 3;
            int cs = e & 7, cc = (e >> 3) & 3, gk = (e >> 5) & 3,
                gq = (e >> 7) & 3, b = (e >> 9) & 1;
            const float* fq = Fg + ((b * 4 + gq) * 4 + cc) * 512 + cs * 64 + part * 8;
            const float* fk = Fg + (((2 + b) * 4 + gk) * 4 + cc) * 512 + cs * 64 + part * 8;
            float a = 0.f;
#pragma unroll
            for (int u = 0; u < 8; ++u) a += fq[u] * fk[u];
            a += __shfl_xor(a, 1);
            a += __shfl_xor(a, 2);
            a += __shfl_xor(a, 4);
            if (part == 0) Dt[e] = a * 0.125f;
        } else {
            int e = slot - 8192;
            int d = e & 63, c = (e >> 6) & 31, b = e >> 11;
            float a = 0.f;
#pragma unroll
            for (int gv = 0; gv < 4; ++gv)
                a += Fg[(((2 + b) * 4 + gv) * 4 + (c >> 3)) * 512 + (c & 7) * 64 + d];
            SFK[e] = 32.f * a;
        }
    }
    __threadfence();
    grid.sync();

    // ---- Phase C: attention.  2 lanes per k (16 c each), 8 k per lane.
    bool mbytes = sniff_mask_bytes((const unsigned int*)maskp);
    for (int vb = blockIdx.x; vb < 1024; vb += nb) {
        if (fill) ((float4*)attnp)[vb * 256 + t] = make_float4(1.f, 1.f, 1.f, 1.f);
        int qb = vb & 63, h = (vb >> 6) & 7, b = vb >> 9;
        int wave = t >> 6, l = t & 63;
        int q = qb * 4 + wave;
        int half = l & 1, klo = l >> 1;
        int g_q = q & 3;
        int i_q = h * 32 + (q >> 3);
        bool up_q = (q & 4) == 0;
        int ak = klo & 3;
        bool up_k = (klo & 4) == 0;

        float sq[16];
        const float* Db = Dt + ((b * 4 + g_q) * 4 + ak) * 32 + half * 16;
#pragma unroll
        for (int j = 0; j < 16; ++j) {
            int cc = half * 2 + (j >> 3);
            int row = g_q * 64 + 30 + cc;
            bool vq = up_q ? (i_q >= 256 - row) : (i_q <= 255 - row);
            sq[j] = vq ? Db[j] : 0.f;
        }

        float A[16];
#pragma unroll
        for (int j = 0; j < 16; ++j) A[j] = 0.f;

        int qrow = (b * 256 + q) * 256;
        for (int r = 0; r < 8; ++r) {
            int k = r * 32 + klo;
            bool masked = mbytes ? (((const unsigned char*)maskp)[qrow + k] != 0)
                                 : (((const int*)maskp)[qrow + k] != 0);
            if (masked) {
#pragma unroll
                for (int j = 0; j < 16; ++j) A[j] += 0.03125f;
                continue;
            }
            int i_k = h * 32 + (k >> 3);
            float s[16];
            float mx = -1e30f;
#pragma unroll
            for (int j = 0; j < 16; ++j) {
                int cc = half * 2 + (j >> 3);
                int row = ak * 64 + 30 + cc;
                bool vk = up_k ? (i_k >= 256 - row) : (i_k <= 255 - row);
                s[j] = vk ? sq[j] : 0.f;
                mx = fmaxf(mx, s[j]);
            }
            mx = fmaxf(mx, __shfl_xor(mx, 1));
            float den = 0.f;
#pragma unroll
            for (int j = 0; j < 16; ++j) { s[j] = __expf(s[j] - mx); den += s[j]; }
            den += __shfl_xor(den, 1);
            float inv = 1.f / den;
#pragma unroll
            for (int j = 0; j < 16; ++j) A[j] += s[j] * inv;
        }

        // reduce over the 32 lane-pairs (offsets 2..32); half stays fixed
#pragma unroll
        for (int off = 2; off < 64; off <<= 1) {
#pragma unroll
            for (int j = 0; j < 16; ++j) A[j] += __shfl_xor(A[j], off);
        }

        // lane 0 holds c 0..15, lane 1 holds c 16..31 (all duplicates agree)
        float* aw = smem + wave * 32;
        if (l < 2) {
#pragma unroll
            for (int j = 0; j < 16; ++j) aw[l * 16 + j] = A[j];
        }
        // same-wave LDS RAW: wave-synchronous, compiler inserts lgkmcnt wait
        float acc = 0.f;
        const float* S = SFK + b * 2048;
#pragma unroll
        for (int c = 0; c < 32; ++c) acc += aw[c] * S[c * 64 + l];
        ctx[(b * 256 + q) * 512 + h * 64 + l] = acc;
    }
    __threadfence();
    grid.sync();

    // ---- Phase D: ymid = ctx @ Wo + bo + Qin (full-K, col-split, 1024 tiles)
    for (int vb = blockIdx.x; vb < 1024; vb += nb) {
        int ro = vb & 63, cq = vb >> 6;
        __syncthreads();
#pragma unroll
        for (int i = 0; i < 16; ++i) {
            int idx = i * 256 + t;
            smem[idx] = ctx[ro * 4096 + idx];     // rows ro*8..ro*8+7 contiguous
        }
        __syncthreads();
        int col = cq * 32 + (t & 31), row = t >> 5;
        float acc = 0.f;
#pragma unroll 8
        for (int j = 0; j < 512; ++j) acc += smem[row * 512 + j] * Wo[j * 512 + col];
        int grow = ro * 8 + row;
        ymid[grow * 512 + col] = acc + bo[col] + Qin[grow * 512 + col];
    }
    __threadfence();
    grid.sync();

    // ---- Phase E: LayerNorm rows of ymid -> out
    for (int vb = blockIdx.x; vb < 512; vb += nb) {
        float y0 = ymid[vb * 512 + t];
        float y1 = ymid[vb * 512 + 256 + t];
        float s1 = y0 + y1, s2 = y0 * y0 + y1 * y1;
#pragma unroll
        for (int off = 1; off < 64; off <<= 1) {
            s1 += __shfl_xor(s1, off);
            s2 += __shfl_xor(s2, off);
        }
        __syncthreads();
        if ((t & 63) == 0) { smem[(t >> 6) * 2] = s1; smem[(t >> 6) * 2 + 1] = s2; }
        __syncthreads();
        float tot1 = smem[0] + smem[2] + smem[4] + smem[6];
        float tot2 = smem[1] + smem[3] + smem[5] + smem[7];
        float mu = tot1 * (1.f / 512.f);
        float var = tot2 * (1.f / 512.f) - mu * mu;
        float rs = rsqrtf(var + LN_EPS);
        out[vb * 512 + t]       = (y0 - mu) * rs * gamma[t]       + beta[t];
        out[vb * 512 + 256 + t] = (y1 - mu) * rs * gamma[t + 256] + beta[t + 256];
    }
}

// ones-fill for plan-B (scratch lived in the attn_out region)
__global__ void k5_fill(float* __restrict__ p, int n) {
    int i = (blockIdx.x * 256 + threadIdx.x) * 4;
    float4 one = make_float4(1.f, 1.f, 1.f, 1.f);
    for (; i < n; i += gridDim.x * 256 * 4) *(float4*)(p + i) = one;
}

extern "C" void kernel_launch(void* const* d_in, const int* in_sizes, int n_in,
                              void* d_out, int out_size, void* d_ws, size_t ws_size,
                              hipStream_t stream) {
    (void)in_sizes; (void)n_in; (void)out_size;
    const float* Qin  = (const float*)d_in[0];
    const float* Kin  = (const float*)d_in[1];
    const void*  mask = d_in[3];
    const float* WQ   = (const float*)d_in[4];
    const float* bQ   = (const float*)d_in[5];
    const float* WK   = (const float*)d_in[6];
    const float* bK   = (const float*)d_in[7];
    const float* Wo   = (const float*)d_in[10];
    const float* bo   = (const float*)d_in[11];
    const float* gamma= (const float*)d_in[12];
    const float* beta = (const float*)d_in[13];

    float* out   = (float*)d_out;
    float* attnp = out + 262144;                  // 1,048,576 floats (output 1)

    const size_t NEED = 562176ull * sizeof(float);
    int fill;
    float* scr;
    if (ws_size >= NEED) { scr = (float*)d_ws; fill = 1; }   // plan A
    else                 { scr = attnp;        fill = 0; }   // plan B

    // grid size: all blocks co-resident (cooperative requirement)
    int dev = 0, numCU = 0, maxBlk = 0;
    hipGetDevice(&dev);
    hipDeviceGetAttribute(&numCU, hipDeviceAttributeMultiprocessorCount, dev);
    hipOccupancyMaxActiveBlocksPerMultiprocessor(&maxBlk, fused_all, 256, 0);
    int G = maxBlk * numCU;
    if (G > 1024) G = 1024;
    if (G < 1) G = 1;

    void* args[] = {
        (void*)&Qin, (void*)&Kin, (void*)&mask,
        (void*)&WQ, (void*)&bQ, (void*)&WK, (void*)&bK,
        (void*)&Wo, (void*)&bo, (void*)&gamma, (void*)&beta,
        (void*)&out, (void*)&attnp, (void*)&scr, (void*)&fill
    };
    hipError_t err = hipLaunchCooperativeKernel((void*)fused_all, dim3(G), dim3(256),
                                                args, 0, stream);
    if (err != hipSuccess) {
        // should not happen; leave output poisoned so the failure is visible
        return;
    }
    if (!fill) k5_fill<<<dim3(256), dim3(256), 0, stream>>>(attnp, 1048576);
}

// Round 5
// 52.934 us; speedup vs baseline: 8.5878x; 8.5878x over previous
//
#include <hip/hip_runtime.h>

#define LN_EPS 1e-5f

// ---------------------------------------------------------------------------
// Index algebra (verified passing rounds 2-4):
//   F[which][b][g][cc][cs*64+d] = P_{which}[b, s_i, h_i*64+d] + bias
//     s_i = (cc<2 ? 240+8*cc : 8*(cc-2)) + cs,  h_i = g*2 + (cc>>1)
//     (equivalently: h even -> s rows 240..255, h odd -> s rows 0..15)
//   Dt[b][gq][gk][cc][cs] = dot64(Fq, Fk) / 8
//   SFK[b][c][d] = 32 * sum_gv FK[b][gv][c>>3][(c&7)*64+d]   (pre-scaled)
//   attn: per (q,k) softmax over 32 c of (vq&vk ? Dt : 0); masked -> 1/32.
//   A[c] = sum_k attn;  ctx[b,q,h*64+d] = sum_c A[c]*SFK[b][c][d].
//   attn_out == 1.0 everywhere.
// Scratch (floats): F 32768 | Dt 1024 | SFK 4096 | ctx 262144 | ymid 262144
//   = 562176 floats (2.2 MB). Plan A: d_ws. Plan B: attn_out region + fill.
// ---------------------------------------------------------------------------

__device__ __forceinline__ bool sniff_mask_bytes(const unsigned int* m) {
    unsigned int acc = 0;
#pragma unroll
    for (int i = 0; i < 16; ++i) acc |= m[i];
    return acc > 1u;
}

// kP: projections -> F.  64 blocks x 512 thr.  Block = (which, b, h_i):
// 16 rows (c2 x cs) x 64 cols (d), full K=512, X staged in LDS.
__global__ __launch_bounds__(512) void kP_proj(
    const float* __restrict__ Qin, const float* __restrict__ Kin,
    const float* __restrict__ WQ, const float* __restrict__ bQ,
    const float* __restrict__ WK, const float* __restrict__ bK,
    float* __restrict__ F)
{
    int bx = blockIdx.x;
    int h_i = bx & 7, b = (bx >> 3) & 1, which = bx >> 4;
    int g = h_i >> 1, cc2 = (h_i & 1) * 2;     // cc = cc2 + c2
    int t = threadIdx.x;

    const float* In   = which ? Kin : Qin;
    const float* W    = which ? WK  : WQ;
    const float* bias = which ? bK  : bQ;

    __shared__ float Xl[16][512];              // rowlocal = c2*8+cs
    // rows: c2=0 -> sbase0, c2=1 -> sbase1
    int sb0 = (h_i & 1) ? 0 : 240;             // + 8*c2
#pragma unroll
    for (int i = 0; i < 4; ++i) {
        int idx = (i * 512 + t);               // 2048 float4 slots
        int rl = idx >> 7, m4 = idx & 127;     // row-local, float4 within row
        int srow = sb0 + (rl >> 3) * 8 + (rl & 7);
        ((float4*)&Xl[rl][0])[m4] =
            ((const float4*)&In[(b * 256 + srow) * 512])[m4];
    }
    __syncthreads();

    int d = t & 63, rr = t >> 6;               // rows rr and rr+8
    int n = h_i * 64 + d;
    float acc0 = 0.f, acc1 = 0.f;
    const float* wp = W + n;
#pragma unroll 8
    for (int m = 0; m < 512; ++m) {
        float w = wp[m * 512];
        acc0 += Xl[rr][m] * w;
        acc1 += Xl[rr + 8][m] * w;
    }
    float bb = bias[n];
    int base = ((which * 2 + b) * 4 + g) * 4;
    // row rr    -> cc = cc2,   cs = rr
    // row rr+8  -> cc = cc2+1, cs = rr
    F[(base + cc2)     * 512 + rr * 64 + d] = acc0 + bb;
    F[(base + cc2 + 1) * 512 + rr * 64 + d] = acc1 + bb;
}

// kC: Dt (8-lane dots + shfl) and SFK (pre-scaled x32).  48 blocks x 256 thr.
__global__ void kC_dtab_sfk(const float* __restrict__ F, float* __restrict__ Dt,
                            float* __restrict__ SFK) {
    int slot = blockIdx.x * 256 + threadIdx.x;
    if (slot < 8192) {
        int part = slot & 7, e = slot >> 3;
        int cs = e & 7, cc = (e >> 3) & 3, gk = (e >> 5) & 3,
            gq = (e >> 7) & 3, b = (e >> 9) & 1;
        const float* fq = F + ((b * 4 + gq) * 4 + cc) * 512 + cs * 64 + part * 8;
        const float* fk = F + (((2 + b) * 4 + gk) * 4 + cc) * 512 + cs * 64 + part * 8;
        float a = 0.f;
#pragma unroll
        for (int u = 0; u < 8; ++u) a += fq[u] * fk[u];
        a += __shfl_xor(a, 1);
        a += __shfl_xor(a, 2);
        a += __shfl_xor(a, 4);
        if (part == 0) Dt[e] = a * 0.125f;
    } else {
        int e = slot - 8192;
        int d = e & 63, c = (e >> 6) & 31, b = e >> 11;
        float a = 0.f;
#pragma unroll
        for (int gv = 0; gv < 4; ++gv)
            a += F[(((2 + b) * 4 + gv) * 4 + (c >> 3)) * 512 + (c & 7) * 64 + d];
        SFK[e] = 32.f * a;
    }
}

// kAttn: 1024 blocks x 256 thr.  Wave per (h,q); 2 lanes per k, 16 c each.
__global__ void kAttn(const float* __restrict__ Dt, const void* __restrict__ maskp,
                      const float* __restrict__ SFK, float* __restrict__ ctx,
                      float* __restrict__ attnp, int fill) {
    __shared__ float aws[4][32];
    int vb = blockIdx.x, t = threadIdx.x;
    if (fill) ((float4*)attnp)[vb * 256 + t] = make_float4(1.f, 1.f, 1.f, 1.f);
    int qb = vb & 63, h = (vb >> 6) & 7, b = vb >> 9;
    int wave = t >> 6, l = t & 63;
    int q = qb * 4 + wave;
    int half = l & 1, klo = l >> 1;
    int g_q = q & 3;
    int i_q = h * 32 + (q >> 3);
    bool up_q = (q & 4) == 0;
    int ak = klo & 3;
    bool up_k = (klo & 4) == 0;

    bool mbytes = sniff_mask_bytes((const unsigned int*)maskp);

    float sq[16];
    const float* Db = Dt + ((b * 4 + g_q) * 4 + ak) * 32 + half * 16;
#pragma unroll
    for (int j = 0; j < 16; ++j) {
        int cc = half * 2 + (j >> 3);
        int row = g_q * 64 + 30 + cc;
        bool vq = up_q ? (i_q >= 256 - row) : (i_q <= 255 - row);
        sq[j] = vq ? Db[j] : 0.f;
    }

    float A[16];
#pragma unroll
    for (int j = 0; j < 16; ++j) A[j] = 0.f;

    int qrow = (b * 256 + q) * 256;
    for (int r = 0; r < 8; ++r) {
        int k = r * 32 + klo;
        bool masked = mbytes ? (((const unsigned char*)maskp)[qrow + k] != 0)
                             : (((const int*)maskp)[qrow + k] != 0);
        if (masked) {
#pragma unroll
            for (int j = 0; j < 16; ++j) A[j] += 0.03125f;
            continue;
        }
        int i_k = h * 32 + (k >> 3);
        float s[16];
        float mx = -1e30f;
#pragma unroll
        for (int j = 0; j < 16; ++j) {
            int cc = half * 2 + (j >> 3);
            int row = ak * 64 + 30 + cc;
            bool vk = up_k ? (i_k >= 256 - row) : (i_k <= 255 - row);
            s[j] = vk ? sq[j] : 0.f;
            mx = fmaxf(mx, s[j]);
        }
        mx = fmaxf(mx, __shfl_xor(mx, 1));
        float den = 0.f;
#pragma unroll
        for (int j = 0; j < 16; ++j) { s[j] = __expf(s[j] - mx); den += s[j]; }
        den += __shfl_xor(den, 1);
        float inv = 1.f / den;
#pragma unroll
        for (int j = 0; j < 16; ++j) A[j] += s[j] * inv;
    }

#pragma unroll
    for (int off = 2; off < 64; off <<= 1) {
#pragma unroll
        for (int j = 0; j < 16; ++j) A[j] += __shfl_xor(A[j], off);
    }

    float* aw = aws[wave];
    if (l < 2) {
#pragma unroll
        for (int j = 0; j < 16; ++j) aw[l * 16 + j] = A[j];
    }
    float acc = 0.f;
    const float* S = SFK + b * 2048;
#pragma unroll
    for (int c = 0; c < 32; ++c) acc += aw[c] * S[c * 64 + l];
    ctx[(b * 256 + q) * 512 + h * 64 + l] = acc;
}

// kG: ymid = ctx @ Wo + bo.  256 blocks x 512 thr.  Block = (colchunk 8, rowchunk 32):
// 16 rows x 64 cols, full K, ctx rows staged in LDS, 2 rows/thread share W loads.
__global__ __launch_bounds__(512) void kG_wo(
    const float* __restrict__ ctx, const float* __restrict__ Wo,
    const float* __restrict__ bo, float* __restrict__ ymid)
{
    int bx = blockIdx.x;
    int cb = bx & 7, rb = bx >> 3;
    int r0 = rb * 16;
    int t = threadIdx.x;

    __shared__ float Cl[16][512];
#pragma unroll
    for (int i = 0; i < 4; ++i) {
        int idx = i * 512 + t;
        int rl = idx >> 7, m4 = idx & 127;
        ((float4*)&Cl[rl][0])[m4] = ((const float4*)&ctx[(r0 + rl) * 512])[m4];
    }
    __syncthreads();

    int col = cb * 64 + (t & 63), r2 = t >> 6;  // rows r2, r2+8
    float acc0 = 0.f, acc1 = 0.f;
    const float* wp = Wo + col;
#pragma unroll 8
    for (int j = 0; j < 512; ++j) {
        float w = wp[j * 512];
        acc0 += Cl[r2][j] * w;
        acc1 += Cl[r2 + 8][j] * w;
    }
    float bb = bo[col];
    ymid[(r0 + r2) * 512 + col]     = acc0 + bb;
    ymid[(r0 + r2 + 8) * 512 + col] = acc1 + bb;
}

// kLN: y = ymid + Qin; LayerNorm -> out.  512 blocks x 256 thr, row per block.
__global__ void kLN(const float* __restrict__ ymid, const float* __restrict__ Qin,
                    const float* __restrict__ gamma, const float* __restrict__ beta,
                    float* __restrict__ out) {
    __shared__ float red[8];
    int row = blockIdx.x, t = threadIdx.x;
    float y0 = ymid[row * 512 + t]       + Qin[row * 512 + t];
    float y1 = ymid[row * 512 + 256 + t] + Qin[row * 512 + 256 + t];
    float s1 = y0 + y1, s2 = y0 * y0 + y1 * y1;
#pragma unroll
    for (int off = 1; off < 64; off <<= 1) {
        s1 += __shfl_xor(s1, off);
        s2 += __shfl_xor(s2, off);
    }
    if ((t & 63) == 0) { red[(t >> 6) * 2] = s1; red[(t >> 6) * 2 + 1] = s2; }
    __syncthreads();
    float tot1 = red[0] + red[2] + red[4] + red[6];
    float tot2 = red[1] + red[3] + red[5] + red[7];
    float mu = tot1 * (1.f / 512.f);
    float var = tot2 * (1.f / 512.f) - mu * mu;
    float rs = rsqrtf(var + LN_EPS);
    out[row * 512 + t]       = (y0 - mu) * rs * gamma[t]       + beta[t];
    out[row * 512 + 256 + t] = (y1 - mu) * rs * gamma[t + 256] + beta[t + 256];
}

// plan-B only: restore attn_out region (which hosted scratch) to 1.0
__global__ void k5_fill(float* __restrict__ p, int n) {
    int i = (blockIdx.x * 256 + threadIdx.x) * 4;
    float4 one = make_float4(1.f, 1.f, 1.f, 1.f);
    for (; i < n; i += gridDim.x * 256 * 4) *(float4*)(p + i) = one;
}

extern "C" void kernel_launch(void* const* d_in, const int* in_sizes, int n_in,
                              void* d_out, int out_size, void* d_ws, size_t ws_size,
                              hipStream_t stream) {
    (void)in_sizes; (void)n_in; (void)out_size;
    const float* Qin  = (const float*)d_in[0];
    const float* Kin  = (const float*)d_in[1];
    const void*  mask = d_in[3];
    const float* WQ   = (const float*)d_in[4];
    const float* bQ   = (const float*)d_in[5];
    const float* WK   = (const float*)d_in[6];
    const float* bK   = (const float*)d_in[7];
    const float* Wo   = (const float*)d_in[10];
    const float* bo   = (const float*)d_in[11];
    const float* gamma= (const float*)d_in[12];
    const float* beta = (const float*)d_in[13];

    float* out   = (float*)d_out;
    float* attnp = out + 262144;                  // 1,048,576 floats (output 1)

    const size_t NEED = 562176ull * sizeof(float);
    int fill;
    float* scr;
    if (ws_size >= NEED) { scr = (float*)d_ws; fill = 1; }   // plan A
    else                 { scr = attnp;        fill = 0; }   // plan B

    float* F    = scr;                            // 32768
    float* Dt   = scr + 32768;                    // 1024
    float* SFK  = scr + 33792;                    // 4096 (pre-scaled x32)
    float* ctx  = scr + 37888;                    // 262144
    float* ymid = scr + 300032;                   // 262144

    kP_proj   <<<dim3(64),   dim3(512), 0, stream>>>(Qin, Kin, WQ, bQ, WK, bK, F);
    kC_dtab_sfk<<<dim3(48),  dim3(256), 0, stream>>>(F, Dt, SFK);
    kAttn     <<<dim3(1024), dim3(256), 0, stream>>>(Dt, mask, SFK, ctx, attnp, fill);
    kG_wo     <<<dim3(256),  dim3(512), 0, stream>>>(ctx, Wo, bo, ymid);
    kLN       <<<dim3(512),  dim3(256), 0, stream>>>(ymid, Qin, gamma, beta, out);
    if (!fill) k5_fill<<<dim3(256), dim3(256), 0, stream>>>(attnp, 1048576);
}

// Round 6
// 46.106 us; speedup vs baseline: 9.8596x; 1.1481x over previous
//
#include <hip/hip_runtime.h>

#define LN_EPS 1e-5f

// ---------------------------------------------------------------------------
// Index algebra (verified passing rounds 2-5):
//   F[which][b][g][cc][cs*64+d] = P_{which}[b, s_i, h_i*64+d] + bias
//     s_i = (cc<2 ? 240+8*cc : 8*(cc-2)) + cs,  h_i = g*2 + (cc>>1)
//   Dt[b][gq][gk][cc][cs] = dot64(Fq, Fk) / 8
//   SFK[b][c][d] = 32 * sum_gv FK[b][gv][c>>3][(c&7)*64+d]   (pre-scaled)
//   attn: per (q,k) softmax over 32 c of (vq&vk ? Dt : 0); masked -> 1/32.
//   A[c] = sum_k attn;  ctx[b,q,h*64+d] = sum_c A[c]*SFK[b][c][d].
//   attn_out == 1.0 everywhere.
// Perf law (r2/r5): 512-deep serial K loops run ~39us regardless of grid;
// split-K to <=128-deep with >=512 blocks (r3 kA) is ~10x faster.
// ---------------------------------------------------------------------------

__device__ __forceinline__ bool sniff_mask_bytes(const unsigned int* m) {
    unsigned int acc = 0;
#pragma unroll
    for (int i = 0; i < 16; ++i) acc |= m[i];
    return acc > 1u;
}

// kA: projection GEMM, split-K (K-chunk 64).  512 blocks x 512 thr.
__global__ __launch_bounds__(512) void kA_proj_part(
    const float* __restrict__ Qin, const float* __restrict__ Kin,
    const float* __restrict__ WQ, const float* __restrict__ WK,
    float* __restrict__ Ppart)
{
    int bx = blockIdx.x;
    int cc = bx & 3, g = (bx >> 2) & 3, b = (bx >> 4) & 1, which = (bx >> 5) & 1, kc = bx >> 6;
    int t = threadIdx.x, d = t & 63, cs = t >> 6;

    const float* In = which ? Kin : Qin;
    const float* W  = which ? WK  : WQ;
    int sbase = (cc < 2) ? (240 + 8 * cc) : (8 * (cc - 2));
    int n = (g * 2 + (cc >> 1)) * 64 + d;

    const float* xrow = In + (b * 256 + sbase + cs) * 512 + kc * 64;
    const float* wcol = W + (kc * 64) * 512 + n;
    float acc = 0.f;
#pragma unroll 8
    for (int m = 0; m < 64; ++m) acc += xrow[m] * wcol[m * 512];

    int fsub = (((which * 2 + b) * 4 + g) * 4 + cc) * 512 + cs * 64 + d;
    Ppart[kc * 32768 + fsub] = acc;
}

// kB: F[f] = sum_kc Ppart[kc][f] + bias.  128 blocks x 256 thr.
__global__ void kB_proj_red(const float* __restrict__ Ppart,
                            const float* __restrict__ bQ, const float* __restrict__ bK,
                            float* __restrict__ F) {
    int f = blockIdx.x * 256 + threadIdx.x;
    float acc = 0.f;
#pragma unroll
    for (int kc = 0; kc < 8; ++kc) acc += Ppart[kc * 32768 + f];
    int which = f >> 14, cc = (f >> 9) & 3, g = (f >> 11) & 3, d = f & 63;
    int n = (g * 2 + (cc >> 1)) * 64 + d;
    F[f] = acc + (which ? bK[n] : bQ[n]);
}

// kC: Dt (8-lane dots + shfl) and SFK (pre-scaled x32).  48 blocks x 256 thr.
__global__ void kC_dtab_sfk(const float* __restrict__ F, float* __restrict__ Dt,
                            float* __restrict__ SFK) {
    int slot = blockIdx.x * 256 + threadIdx.x;
    if (slot < 8192) {
        int part = slot & 7, e = slot >> 3;
        int cs = e & 7, cc = (e >> 3) & 3, gk = (e >> 5) & 3,
            gq = (e >> 7) & 3, b = (e >> 9) & 1;
        const float* fq = F + ((b * 4 + gq) * 4 + cc) * 512 + cs * 64 + part * 8;
        const float* fk = F + (((2 + b) * 4 + gk) * 4 + cc) * 512 + cs * 64 + part * 8;
        float a = 0.f;
#pragma unroll
        for (int u = 0; u < 8; ++u) a += fq[u] * fk[u];
        a += __shfl_xor(a, 1);
        a += __shfl_xor(a, 2);
        a += __shfl_xor(a, 4);
        if (part == 0) Dt[e] = a * 0.125f;
    } else {
        int e = slot - 8192;
        int d = e & 63, c = (e >> 6) & 31, b = e >> 11;
        float a = 0.f;
#pragma unroll
        for (int gv = 0; gv < 4; ++gv)
            a += F[(((2 + b) * 4 + gv) * 4 + (c >> 3)) * 512 + (c & 7) * 64 + d];
        SFK[e] = 32.f * a;
    }
}

// kAttn: 1024 blocks x 256 thr.  Wave per (h,q); 2 lanes per k, 16 c each.
__global__ void kAttn(const float* __restrict__ Dt, const void* __restrict__ maskp,
                      const float* __restrict__ SFK, float* __restrict__ ctx,
                      float* __restrict__ attnp, int fill) {
    __shared__ float aws[4][32];
    int vb = blockIdx.x, t = threadIdx.x;
    if (fill) ((float4*)attnp)[vb * 256 + t] = make_float4(1.f, 1.f, 1.f, 1.f);
    int qb = vb & 63, h = (vb >> 6) & 7, b = vb >> 9;
    int wave = t >> 6, l = t & 63;
    int q = qb * 4 + wave;
    int half = l & 1, klo = l >> 1;
    int g_q = q & 3;
    int i_q = h * 32 + (q >> 3);
    bool up_q = (q & 4) == 0;
    int ak = klo & 3;
    bool up_k = (klo & 4) == 0;

    bool mbytes = sniff_mask_bytes((const unsigned int*)maskp);

    float sq[16];
    const float* Db = Dt + ((b * 4 + g_q) * 4 + ak) * 32 + half * 16;
#pragma unroll
    for (int j = 0; j < 16; ++j) {
        int cc = half * 2 + (j >> 3);
        int row = g_q * 64 + 30 + cc;
        bool vq = up_q ? (i_q >= 256 - row) : (i_q <= 255 - row);
        sq[j] = vq ? Db[j] : 0.f;
    }

    float A[16];
#pragma unroll
    for (int j = 0; j < 16; ++j) A[j] = 0.f;

    int qrow = (b * 256 + q) * 256;
    for (int r = 0; r < 8; ++r) {
        int k = r * 32 + klo;
        bool masked = mbytes ? (((const unsigned char*)maskp)[qrow + k] != 0)
                             : (((const int*)maskp)[qrow + k] != 0);
        if (masked) {
#pragma unroll
            for (int j = 0; j < 16; ++j) A[j] += 0.03125f;
            continue;
        }
        int i_k = h * 32 + (k >> 3);
        float s[16];
        float mx = -1e30f;
#pragma unroll
        for (int j = 0; j < 16; ++j) {
            int cc = half * 2 + (j >> 3);
            int row = ak * 64 + 30 + cc;
            bool vk = up_k ? (i_k >= 256 - row) : (i_k <= 255 - row);
            s[j] = vk ? sq[j] : 0.f;
            mx = fmaxf(mx, s[j]);
        }
        mx = fmaxf(mx, __shfl_xor(mx, 1));
        float den = 0.f;
#pragma unroll
        for (int j = 0; j < 16; ++j) { s[j] = __expf(s[j] - mx); den += s[j]; }
        den += __shfl_xor(den, 1);
        float inv = 1.f / den;
#pragma unroll
        for (int j = 0; j < 16; ++j) A[j] += s[j] * inv;
    }

#pragma unroll
    for (int off = 2; off < 64; off <<= 1) {
#pragma unroll
        for (int j = 0; j < 16; ++j) A[j] += __shfl_xor(A[j], off);
    }

    float* aw = aws[wave];
    if (l < 2) {
#pragma unroll
        for (int j = 0; j < 16; ++j) aw[l * 16 + j] = A[j];
    }
    float acc = 0.f;
    const float* S = SFK + b * 2048;
#pragma unroll
    for (int c = 0; c < 32; ++c) acc += aw[c] * S[c * 64 + l];
    ctx[(b * 256 + q) * 512 + h * 64 + l] = acc;
}

// kG2: Wo GEMM, split-K.  grid = NC x (16 rowb x 8 colb), 256 thr.
// Tile 32 rows x 64 cols, K-chunk KCH = 512/NC, ctx chunk staged in LDS.
// Thread: col = colb*64 + (t&63), rows rgrp*8..+7 -> 8 accumulators.
__global__ __launch_bounds__(256) void kG2_wo_part(
    const float* __restrict__ ctx, const float* __restrict__ Wo,
    float* __restrict__ Wpart, int KCH, int sh /* log2(KCH/4) */)
{
    __shared__ float Cl[32][256];              // supports KCH<=256
    int bx = blockIdx.x;
    int colb = bx & 7, rowb = (bx >> 3) & 15, kc = bx >> 7;
    int r0 = rowb * 32, k0 = kc * KCH;
    int t = threadIdx.x;

    int nf4 = (32 * KCH) >> 2;
    int m4mask = (1 << sh) - 1;
    for (int i = t; i < nf4; i += 256) {
        int rl = i >> sh, k4 = i & m4mask;
        ((float4*)&Cl[rl][0])[k4] = ((const float4*)&ctx[(r0 + rl) * 512 + k0])[k4];
    }
    __syncthreads();

    int col = colb * 64 + (t & 63), rgrp = t >> 6;
    float acc[8];
#pragma unroll
    for (int u = 0; u < 8; ++u) acc[u] = 0.f;
    const float* wp = Wo + k0 * 512 + col;
#pragma unroll 8
    for (int k = 0; k < KCH; ++k) {
        float w = wp[k * 512];
#pragma unroll
        for (int u = 0; u < 8; ++u) acc[u] += Cl[rgrp * 8 + u][k] * w;
    }
#pragma unroll
    for (int u = 0; u < 8; ++u)
        Wpart[(kc * 512 + r0 + rgrp * 8 + u) * 512 + col] = acc[u];
}

// kLN2: reduce NC partials + bias + residual + LayerNorm.  512 blocks x 256 thr.
__global__ void kLN2(const float* __restrict__ Wpart, const float* __restrict__ bo,
                     const float* __restrict__ Qin, const float* __restrict__ gamma,
                     const float* __restrict__ beta, float* __restrict__ out, int NC) {
    __shared__ float red[8];
    int row = blockIdx.x, t = threadIdx.x;
    float y0 = bo[t]       + Qin[row * 512 + t];
    float y1 = bo[t + 256] + Qin[row * 512 + 256 + t];
    for (int kc = 0; kc < NC; ++kc) {
        const float* wp = Wpart + (kc * 512 + row) * 512;
        y0 += wp[t];
        y1 += wp[t + 256];
    }
    float s1 = y0 + y1, s2 = y0 * y0 + y1 * y1;
#pragma unroll
    for (int off = 1; off < 64; off <<= 1) {
        s1 += __shfl_xor(s1, off);
        s2 += __shfl_xor(s2, off);
    }
    if ((t & 63) == 0) { red[(t >> 6) * 2] = s1; red[(t >> 6) * 2 + 1] = s2; }
    __syncthreads();
    float tot1 = red[0] + red[2] + red[4] + red[6];
    float tot2 = red[1] + red[3] + red[5] + red[7];
    float mu = tot1 * (1.f / 512.f);
    float var = tot2 * (1.f / 512.f) - mu * mu;
    float rs = rsqrtf(var + LN_EPS);
    out[row * 512 + t]       = (y0 - mu) * rs * gamma[t]       + beta[t];
    out[row * 512 + 256 + t] = (y1 - mu) * rs * gamma[t + 256] + beta[t + 256];
}

// plan-B only: restore attn_out region (which hosted scratch) to 1.0
__global__ void k5_fill(float* __restrict__ p, int n) {
    int i = (blockIdx.x * 256 + threadIdx.x) * 4;
    float4 one = make_float4(1.f, 1.f, 1.f, 1.f);
    for (; i < n; i += gridDim.x * 256 * 4) *(float4*)(p + i) = one;
}

extern "C" void kernel_launch(void* const* d_in, const int* in_sizes, int n_in,
                              void* d_out, int out_size, void* d_ws, size_t ws_size,
                              hipStream_t stream) {
    (void)in_sizes; (void)n_in; (void)out_size;
    const float* Qin  = (const float*)d_in[0];
    const float* Kin  = (const float*)d_in[1];
    const void*  mask = d_in[3];
    const float* WQ   = (const float*)d_in[4];
    const float* bQ   = (const float*)d_in[5];
    const float* WK   = (const float*)d_in[6];
    const float* bK   = (const float*)d_in[7];
    const float* Wo   = (const float*)d_in[10];
    const float* bo   = (const float*)d_in[11];
    const float* gamma= (const float*)d_in[12];
    const float* beta = (const float*)d_in[13];

    float* out   = (float*)d_out;
    float* attnp = out + 262144;                  // 1,048,576 floats (output 1)

    const size_t NEED_A = (562176ull + 8ull * 262144ull) * 4ull;  // ~10.6 MB
    if (ws_size >= NEED_A) {
        // Plan A: everything in d_ws, NC=8 (64-deep K chunks).
        float* ws    = (float*)d_ws;
        float* Ppart = ws;                        // 262144
        float* F     = ws + 262144;               // 32768
        float* Dt    = ws + 294912;               // 1024
        float* SFK   = ws + 295936;               // 4096
        float* ctx   = ws + 300032;               // 262144
        float* Wpart = ws + 562176;               // 8*262144
        const int NC = 8, KCH = 64, SH = 4;

        kA_proj_part<<<dim3(512),      dim3(512), 0, stream>>>(Qin, Kin, WQ, WK, Ppart);
        kB_proj_red <<<dim3(128),      dim3(256), 0, stream>>>(Ppart, bQ, bK, F);
        kC_dtab_sfk <<<dim3(48),       dim3(256), 0, stream>>>(F, Dt, SFK);
        kAttn       <<<dim3(1024),     dim3(256), 0, stream>>>(Dt, mask, SFK, ctx, attnp, 1);
        kG2_wo_part <<<dim3(128 * NC), dim3(256), 0, stream>>>(ctx, Wo, Wpart, KCH, SH);
        kLN2        <<<dim3(512),      dim3(256), 0, stream>>>(Wpart, bo, Qin, gamma, beta, out, NC);
    } else {
        // Plan B: scratch in attn_out region (1,048,576 floats), NC=2.
        // Ppart/F/Dt/SFK dead before kG2 overwrites [0, 524288); ctx kept at tail.
        float* Ppart = attnp;                     // [0, 262144)
        float* F     = attnp + 262144;            // [262144, 294912)
        float* Dt    = attnp + 294912;            // [294912, 295936)
        float* SFK   = attnp + 295936;            // [295936, 300032)
        float* ctx   = attnp + 786432;            // [786432, 1048576)
        float* Wpart = attnp;                     // [0, 524288)
        const int NC = 2, KCH = 256, SH = 6;

        kA_proj_part<<<dim3(512),      dim3(512), 0, stream>>>(Qin, Kin, WQ, WK, Ppart);
        kB_proj_red <<<dim3(128),      dim3(256), 0, stream>>>(Ppart, bQ, bK, F);
        kC_dtab_sfk <<<dim3(48),       dim3(256), 0, stream>>>(F, Dt, SFK);
        kAttn       <<<dim3(1024),     dim3(256), 0, stream>>>(Dt, mask, SFK, ctx, attnp, 0);
        kG2_wo_part <<<dim3(128 * NC), dim3(256), 0, stream>>>(ctx, Wo, Wpart, KCH, SH);
        kLN2        <<<dim3(512),      dim3(256), 0, stream>>>(Wpart, bo, Qin, gamma, beta, out, NC);
        k5_fill     <<<dim3(256),      dim3(256), 0, stream>>>(attnp, 1048576);
    }
}